// Round 1
// baseline (2121.548 us; speedup 1.0000x reference)
//
#include <hip/hip_runtime.h>

#define EPS 1e-9f

constexpr int B_ = 8, N_ = 2048, M_ = 2048;
constexpr int THREADS = 256;
constexpr int WAVES = THREADS / 64;              // 4
constexpr int ROWS_PER_WAVE = 8;
constexpr int ROWS_PER_BLOCK = WAVES * ROWS_PER_WAVE;   // 32
constexpr int BLOCKS_PER_BATCH = N_ / ROWS_PER_BLOCK;   // 64
constexpr int GRID = B_ * BLOCKS_PER_BATCH;             // 512

__global__ __launch_bounds__(THREADS) void init_kernel(float* rL, float* rR,
                                                       float* ss, float* out) {
    int i = blockIdx.x * blockDim.x + threadIdx.x;
    if (i < B_ * N_) { rL[i] = 1.f; rR[i] = 1.f; ss[i] = 0.f; }
    if (i < B_) out[i] = 0.f;
}

// Phase 1: per row n: rowsum = sum_m exp(L*d2)*rR[m]; ss[m] += rowterm * rL[n]/(rowsum+EPS)
__global__ __launch_bounds__(THREADS) void phase1(
        const float* __restrict__ xyz1, const float* __restrict__ xyz2,
        const float* __restrict__ rL, const float* __restrict__ rR,
        float* __restrict__ ss, float* __restrict__ rowsum_g, float level)
{
    __shared__ float4 sp[M_];    // x,y,z,rR
    __shared__ float  ssl[M_];   // block-local column sums
    const int b  = blockIdx.x / BLOCKS_PER_BATCH;
    const int n0 = (blockIdx.x % BLOCKS_PER_BATCH) * ROWS_PER_BLOCK;
    const int tid = threadIdx.x;

    const float* x2  = xyz2 + (size_t)b * M_ * 3;
    const float* rrb = rR + b * M_;
    for (int m = tid; m < M_; m += THREADS) {
        sp[m] = make_float4(x2[3*m], x2[3*m+1], x2[3*m+2], rrb[m]);
        ssl[m] = 0.f;
    }
    __syncthreads();

    const int wave = tid >> 6, lane = tid & 63;
    for (int r = 0; r < ROWS_PER_WAVE; ++r) {
        const int n = n0 + wave * ROWS_PER_WAVE + r;
        const float* p1 = xyz1 + ((size_t)b * N_ + n) * 3;
        const float x1 = p1[0], y1 = p1[1], z1 = p1[2];
        float a[32];
        float partial = 0.f;
        #pragma unroll
        for (int k = 0; k < 32; ++k) {
            const int m = lane + (k << 6);
            const float4 p = sp[m];
            const float dx = x1 - p.x, dy = y1 - p.y, dz = z1 - p.z;
            const float d2 = dx*dx + dy*dy + dz*dz;
            const float e = __expf(level * d2) * p.w;
            a[k] = e;
            partial += e;
        }
        #pragma unroll
        for (int off = 32; off >= 1; off >>= 1)
            partial += __shfl_xor(partial, off, 64);
        if (lane == 0) rowsum_g[b * N_ + n] = partial;
        const float f = rL[b * N_ + n] / (partial + EPS);
        #pragma unroll
        for (int k = 0; k < 32; ++k)
            atomicAdd(&ssl[lane + (k << 6)], a[k] * f);
    }
    __syncthreads();
    for (int m = tid; m < M_; m += THREADS)
        atomicAdd(&ss[b * M_ + m], ssl[m]);
}

// Phase 2: g[m] = rR[m]*min(rR/(ss+EPS),1); per row: cost += f*sum(e*g*dist);
//          rL[n] = max(rL - f*sum(e*g), 0)
__global__ __launch_bounds__(THREADS) void phase2(
        const float* __restrict__ xyz1, const float* __restrict__ xyz2,
        float* __restrict__ rL, const float* __restrict__ rR,
        const float* __restrict__ ss, const float* __restrict__ rowsum_g,
        float* __restrict__ out, float level)
{
    __shared__ float4 sp[M_];    // x,y,z,g
    __shared__ float  blockcost;
    const int b  = blockIdx.x / BLOCKS_PER_BATCH;
    const int n0 = (blockIdx.x % BLOCKS_PER_BATCH) * ROWS_PER_BLOCK;
    const int tid = threadIdx.x;

    const float* x2 = xyz2 + (size_t)b * M_ * 3;
    for (int m = tid; m < M_; m += THREADS) {
        const float rr = rR[b * M_ + m];
        const float s  = ss[b * M_ + m];
        const float ratio = fminf(rr / (s + EPS), 1.f);
        sp[m] = make_float4(x2[3*m], x2[3*m+1], x2[3*m+2], rr * ratio);
    }
    if (tid == 0) blockcost = 0.f;
    __syncthreads();

    const int wave = tid >> 6, lane = tid & 63;
    for (int r = 0; r < ROWS_PER_WAVE; ++r) {
        const int n = n0 + wave * ROWS_PER_WAVE + r;
        const float* p1 = xyz1 + ((size_t)b * N_ + n) * 3;
        const float x1 = p1[0], y1 = p1[1], z1 = p1[2];
        float accd = 0.f, accc = 0.f;
        #pragma unroll
        for (int k = 0; k < 32; ++k) {
            const int m = lane + (k << 6);
            const float4 p = sp[m];
            const float dx = x1 - p.x, dy = y1 - p.y, dz = z1 - p.z;
            const float d2 = dx*dx + dy*dy + dz*dz;
            const float e = __expf(level * d2) * p.w;
            accd += e;
            accc += e * sqrtf(fmaxf(d2, 1e-20f));
        }
        #pragma unroll
        for (int off = 32; off >= 1; off >>= 1) {
            accd += __shfl_xor(accd, off, 64);
            accc += __shfl_xor(accc, off, 64);
        }
        if (lane == 0) {
            const int idx = b * N_ + n;
            const float f = rL[idx] / (rowsum_g[idx] + EPS);
            rL[idx] = fmaxf(rL[idx] - f * accd, 0.f);
            atomicAdd(&blockcost, f * accc);
        }
    }
    __syncthreads();
    if (tid == 0) atomicAdd(&out[b], blockcost);
}

// End-of-step: rR[m] = max(rR - ss*ratio, 0); ss = 0
__global__ __launch_bounds__(THREADS) void update_rR(float* rR, float* ss) {
    int i = blockIdx.x * blockDim.x + threadIdx.x;
    if (i < B_ * M_) {
        const float rr = rR[i], s = ss[i];
        const float ratio = fminf(rr / (s + EPS), 1.f);
        rR[i] = fmaxf(rr - s * ratio, 0.f);
        ss[i] = 0.f;
    }
}

extern "C" void kernel_launch(void* const* d_in, const int* in_sizes, int n_in,
                              void* d_out, int out_size, void* d_ws, size_t ws_size,
                              hipStream_t stream) {
    const float* xyz1 = (const float*)d_in[0];
    const float* xyz2 = (const float*)d_in[1];
    float* out = (float*)d_out;
    float* ws = (float*)d_ws;
    float* rL     = ws;
    float* rR     = ws + B_ * N_;
    float* ss     = ws + 2 * B_ * N_;
    float* rowsum = ws + 3 * B_ * N_;

    init_kernel<<<(B_ * N_ + THREADS - 1) / THREADS, THREADS, 0, stream>>>(rL, rR, ss, out);

    static const float levels[10] = {
        -16384.f, -4096.f, -1024.f, -256.f, -64.f,
        -16.f, -4.f, -1.f, -0.25f, 0.f
    };
    for (int s = 0; s < 10; ++s) {
        phase1<<<GRID, THREADS, 0, stream>>>(xyz1, xyz2, rL, rR, ss, rowsum, levels[s]);
        phase2<<<GRID, THREADS, 0, stream>>>(xyz1, xyz2, rL, rR, ss, rowsum, out, levels[s]);
        update_rR<<<(B_ * M_ + THREADS - 1) / THREADS, THREADS, 0, stream>>>(rR, ss);
    }
}

// Round 2
// 1609.961 us; speedup vs baseline: 1.3178x; 1.3178x over previous
//
#include <hip/hip_runtime.h>

#define EPS 1e-9f

constexpr int B_ = 8, N_ = 2048, M_ = 2048;
constexpr int THREADS = 256;
constexpr int WAVES = THREADS / 64;              // 4
constexpr int ROWS_PER_WAVE = 8;
constexpr int ROWS_PER_BLOCK = WAVES * ROWS_PER_WAVE;   // 32
constexpr int BLOCKS_PER_BATCH = N_ / ROWS_PER_BLOCK;   // 64
constexpr int GRID = B_ * BLOCKS_PER_BATCH;             // 512

__global__ __launch_bounds__(THREADS) void init_kernel(float* rL, float* rR,
                                                       float* ss, float* out) {
    int i = blockIdx.x * blockDim.x + threadIdx.x;
    if (i < B_ * N_) { rL[i] = 1.f; rR[i] = 1.f; ss[i] = 0.f; }
    if (i < B_) out[i] = 0.f;
}

// Phase 1: per row n: rowsum = sum_m exp(L*d2)*rR[m]; ss[m] += sum_n a[n,m]*rL[n]/(rowsum+EPS)
// Column sums accumulated in REGISTERS per wave (lane owns cols lane+64k), then
// per-wave LDS slices, then one global atomic per column per block. No LDS atomics.
__global__ __launch_bounds__(THREADS) void phase1(
        const float* __restrict__ xyz1, const float* __restrict__ xyz2,
        const float* __restrict__ rL, const float* __restrict__ rR,
        float* __restrict__ ss, float* __restrict__ rowsum_g, float level)
{
    __shared__ float4 sp[M_];           // x,y,z,rR           (32 KB)
    __shared__ float  ssl[WAVES][M_];   // per-wave col sums  (32 KB)
    const int b  = blockIdx.x / BLOCKS_PER_BATCH;
    const int n0 = (blockIdx.x % BLOCKS_PER_BATCH) * ROWS_PER_BLOCK;
    const int tid = threadIdx.x;

    const float* x2  = xyz2 + (size_t)b * M_ * 3;
    const float* rrb = rR + b * M_;
    for (int m = tid; m < M_; m += THREADS)
        sp[m] = make_float4(x2[3*m], x2[3*m+1], x2[3*m+2], rrb[m]);
    __syncthreads();

    const int wave = tid >> 6, lane = tid & 63;
    const int nw = n0 + wave * ROWS_PER_WAVE;

    // Prefetch wave-uniform row data (scalar loads, pipelined)
    float rl[ROWS_PER_WAVE], x1v[ROWS_PER_WAVE], y1v[ROWS_PER_WAVE], z1v[ROWS_PER_WAVE];
    #pragma unroll
    for (int r = 0; r < ROWS_PER_WAVE; ++r) {
        const int idx = b * N_ + nw + r;
        rl[r] = rL[idx];
        const float* p1 = xyz1 + (size_t)idx * 3;
        x1v[r] = p1[0]; y1v[r] = p1[1]; z1v[r] = p1[2];
    }

    float ssp[32];
    #pragma unroll
    for (int k = 0; k < 32; ++k) ssp[k] = 0.f;

    #pragma unroll
    for (int r = 0; r < ROWS_PER_WAVE; ++r) {
        const float x1 = x1v[r], y1 = y1v[r], z1 = z1v[r];
        float a[32];
        float partial = 0.f;
        #pragma unroll
        for (int k = 0; k < 32; ++k) {
            const float4 p = sp[lane + (k << 6)];
            const float dx = x1 - p.x, dy = y1 - p.y, dz = z1 - p.z;
            const float d2 = dx*dx + dy*dy + dz*dz;
            const float e = __expf(level * d2) * p.w;
            a[k] = e;
            partial += e;
        }
        #pragma unroll
        for (int off = 32; off >= 1; off >>= 1)
            partial += __shfl_xor(partial, off, 64);
        if (lane == 0) rowsum_g[b * N_ + nw + r] = partial;
        const float f = rl[r] / (partial + EPS);
        #pragma unroll
        for (int k = 0; k < 32; ++k)
            ssp[k] += a[k] * f;
    }

    #pragma unroll
    for (int k = 0; k < 32; ++k)
        ssl[wave][lane + (k << 6)] = ssp[k];
    __syncthreads();

    for (int m = tid; m < M_; m += THREADS) {
        const float s = ssl[0][m] + ssl[1][m] + ssl[2][m] + ssl[3][m];
        atomicAdd(&ss[b * M_ + m], s);
    }
}

// Phase 2: g[m] = rR[m]*min(rR/(ss+EPS),1); per row: cost += f*sum(e*g*dist);
//          rL[n] = max(rL - f*sum(e*g), 0)
__global__ __launch_bounds__(THREADS) void phase2(
        const float* __restrict__ xyz1, const float* __restrict__ xyz2,
        float* __restrict__ rL, const float* __restrict__ rR,
        const float* __restrict__ ss, const float* __restrict__ rowsum_g,
        float* __restrict__ out, float level)
{
    __shared__ float4 sp[M_];    // x,y,z,g
    __shared__ float  blockcost;
    const int b  = blockIdx.x / BLOCKS_PER_BATCH;
    const int n0 = (blockIdx.x % BLOCKS_PER_BATCH) * ROWS_PER_BLOCK;
    const int tid = threadIdx.x;

    const float* x2 = xyz2 + (size_t)b * M_ * 3;
    for (int m = tid; m < M_; m += THREADS) {
        const float rr = rR[b * M_ + m];
        const float s  = ss[b * M_ + m];
        const float ratio = fminf(rr / (s + EPS), 1.f);
        sp[m] = make_float4(x2[3*m], x2[3*m+1], x2[3*m+2], rr * ratio);
    }
    if (tid == 0) blockcost = 0.f;
    __syncthreads();

    const int wave = tid >> 6, lane = tid & 63;
    const int nw = n0 + wave * ROWS_PER_WAVE;

    float rl[ROWS_PER_WAVE], rs[ROWS_PER_WAVE];
    float x1v[ROWS_PER_WAVE], y1v[ROWS_PER_WAVE], z1v[ROWS_PER_WAVE];
    #pragma unroll
    for (int r = 0; r < ROWS_PER_WAVE; ++r) {
        const int idx = b * N_ + nw + r;
        rl[r] = rL[idx];
        rs[r] = rowsum_g[idx];
        const float* p1 = xyz1 + (size_t)idx * 3;
        x1v[r] = p1[0]; y1v[r] = p1[1]; z1v[r] = p1[2];
    }

    #pragma unroll
    for (int r = 0; r < ROWS_PER_WAVE; ++r) {
        const float x1 = x1v[r], y1 = y1v[r], z1 = z1v[r];
        float accd = 0.f, accc = 0.f;
        #pragma unroll
        for (int k = 0; k < 32; ++k) {
            const float4 p = sp[lane + (k << 6)];
            const float dx = x1 - p.x, dy = y1 - p.y, dz = z1 - p.z;
            const float d2 = dx*dx + dy*dy + dz*dz;
            const float e = __expf(level * d2) * p.w;
            accd += e;
            accc += e * sqrtf(fmaxf(d2, 1e-20f));
        }
        #pragma unroll
        for (int off = 32; off >= 1; off >>= 1) {
            accd += __shfl_xor(accd, off, 64);
            accc += __shfl_xor(accc, off, 64);
        }
        if (lane == 0) {
            const int idx = b * N_ + nw + r;
            const float f = rl[r] / (rs[r] + EPS);
            rL[idx] = fmaxf(rl[r] - f * accd, 0.f);
            atomicAdd(&blockcost, f * accc);
        }
    }
    __syncthreads();
    if (tid == 0) atomicAdd(&out[b], blockcost);
}

// End-of-step: rR[m] = max(rR - ss*ratio, 0); ss = 0
__global__ __launch_bounds__(THREADS) void update_rR(float* rR, float* ss) {
    int i = blockIdx.x * blockDim.x + threadIdx.x;
    if (i < B_ * M_) {
        const float rr = rR[i], s = ss[i];
        const float ratio = fminf(rr / (s + EPS), 1.f);
        rR[i] = fmaxf(rr - s * ratio, 0.f);
        ss[i] = 0.f;
    }
}

extern "C" void kernel_launch(void* const* d_in, const int* in_sizes, int n_in,
                              void* d_out, int out_size, void* d_ws, size_t ws_size,
                              hipStream_t stream) {
    const float* xyz1 = (const float*)d_in[0];
    const float* xyz2 = (const float*)d_in[1];
    float* out = (float*)d_out;
    float* ws = (float*)d_ws;
    float* rL     = ws;
    float* rR     = ws + B_ * N_;
    float* ss     = ws + 2 * B_ * N_;
    float* rowsum = ws + 3 * B_ * N_;

    init_kernel<<<(B_ * N_ + THREADS - 1) / THREADS, THREADS, 0, stream>>>(rL, rR, ss, out);

    static const float levels[10] = {
        -16384.f, -4096.f, -1024.f, -256.f, -64.f,
        -16.f, -4.f, -1.f, -0.25f, 0.f
    };
    for (int s = 0; s < 10; ++s) {
        phase1<<<GRID, THREADS, 0, stream>>>(xyz1, xyz2, rL, rR, ss, rowsum, levels[s]);
        phase2<<<GRID, THREADS, 0, stream>>>(xyz1, xyz2, rL, rR, ss, rowsum, out, levels[s]);
        update_rR<<<(B_ * M_ + THREADS - 1) / THREADS, THREADS, 0, stream>>>(rR, ss);
    }
}

// Round 3
// 638.525 us; speedup vs baseline: 3.3226x; 2.5214x over previous
//
#include <hip/hip_runtime.h>

#define EPS 1e-9f

constexpr int B_ = 8, N_ = 2048, M_ = 2048;
constexpr int THREADS = 256;
constexpr int WAVES = THREADS / 64;                     // 4
constexpr int ROWS_PER_WAVE = 4;
constexpr int ROWS_PER_BLOCK = WAVES * ROWS_PER_WAVE;   // 16
constexpr int BLOCKS_PER_BATCH = N_ / ROWS_PER_BLOCK;   // 128
constexpr int GRID = B_ * BLOCKS_PER_BATCH;             // 1024

__global__ __launch_bounds__(THREADS) void init_kernel(float* rL, float* rR0,
                                                       float* ss0, float* ss1,
                                                       float* out) {
    int i = blockIdx.x * blockDim.x + threadIdx.x;
    if (i < B_ * N_) { rL[i] = 1.f; rR0[i] = 1.f; ss0[i] = 0.f; ss1[i] = 0.f; }
    if (i < B_) out[i] = 0.f;
}

// Phase 1: per row n: rowsum = sum_m exp(L*d2)*rR[m];
//          ss[m] += sum_n e[n,m] * rL[n]/(rowsum+EPS)
// Register col-sums per wave; per-wave LDS slices OVERLAID on sp (barrier-safe);
// one global atomic per column per block. Row loop unroll(1) to cap VGPRs.
__global__ __launch_bounds__(THREADS) void phase1(
        const float* __restrict__ xyz1, const float* __restrict__ xyz2,
        const float* __restrict__ rL, const float* __restrict__ rR,
        float* __restrict__ ss, float* __restrict__ rowsum_g, float level)
{
    __shared__ float4 sp[M_];                 // 32 KB: x,y,z,rR -> later ssl[4][M_]
    float* ssl = (float*)sp;                  // overlay after main loop
    const int b  = blockIdx.x / BLOCKS_PER_BATCH;
    const int n0 = (blockIdx.x % BLOCKS_PER_BATCH) * ROWS_PER_BLOCK;
    const int tid = threadIdx.x;

    const float* x2  = xyz2 + (size_t)b * M_ * 3;
    const float* rrb = rR + b * M_;
    for (int m = tid; m < M_; m += THREADS)
        sp[m] = make_float4(x2[3*m], x2[3*m+1], x2[3*m+2], rrb[m]);
    __syncthreads();

    const int wave = tid >> 6, lane = tid & 63;
    const int nw = n0 + wave * ROWS_PER_WAVE;

    float ssp[32];
    #pragma unroll
    for (int k = 0; k < 32; ++k) ssp[k] = 0.f;

    #pragma unroll 1
    for (int r = 0; r < ROWS_PER_WAVE; ++r) {
        const int idx = b * N_ + nw + r;
        const float* p1 = xyz1 + (size_t)idx * 3;
        const float x1 = p1[0], y1 = p1[1], z1 = p1[2];
        const float rl = rL[idx];
        float a[32];
        float partial = 0.f;
        #pragma unroll
        for (int k = 0; k < 32; ++k) {
            const float4 p = sp[lane + (k << 6)];
            const float dx = x1 - p.x, dy = y1 - p.y, dz = z1 - p.z;
            const float d2 = dx*dx + dy*dy + dz*dz;
            const float e = __expf(level * d2) * p.w;
            a[k] = e;
            partial += e;
        }
        #pragma unroll
        for (int off = 32; off >= 1; off >>= 1)
            partial += __shfl_xor(partial, off, 64);
        if (lane == 0) rowsum_g[idx] = partial;
        const float f = rl / (partial + EPS);
        #pragma unroll
        for (int k = 0; k < 32; ++k)
            ssp[k] += a[k] * f;
    }

    __syncthreads();   // sp reads complete everywhere; safe to overlay
    #pragma unroll
    for (int k = 0; k < 32; ++k)
        ssl[wave * M_ + lane + (k << 6)] = ssp[k];
    __syncthreads();

    for (int m = tid; m < M_; m += THREADS) {
        const float s = ssl[0 * M_ + m] + ssl[1 * M_ + m]
                      + ssl[2 * M_ + m] + ssl[3 * M_ + m];
        atomicAdd(&ss[b * M_ + m], s);
    }
}

// Phase 2: g[m] = rR[m]*min(rR/(ss+EPS),1); per row: cost += f*sum(e*g*dist);
//          rL[n] = max(rL - f*sum(e*g), 0).
// Designated block per batch also writes rR_next = max(rR - ss*ratio, 0) and
// zeroes ss_next (the buffer phase1 of step s+1 accumulates into) — replaces
// the separate update_rR kernel via double buffering.
__global__ __launch_bounds__(THREADS) void phase2(
        const float* __restrict__ xyz1, const float* __restrict__ xyz2,
        float* __restrict__ rL, const float* __restrict__ rR,
        float* __restrict__ rR_next, const float* __restrict__ ss,
        float* __restrict__ ss_next, const float* __restrict__ rowsum_g,
        float* __restrict__ out, float level)
{
    __shared__ float4 sp[M_];        // x,y,z,g
    __shared__ float  wcost[WAVES];
    const int b  = blockIdx.x / BLOCKS_PER_BATCH;
    const int blk_in_b = blockIdx.x % BLOCKS_PER_BATCH;
    const int n0 = blk_in_b * ROWS_PER_BLOCK;
    const int tid = threadIdx.x;
    const bool designated = (blk_in_b == 0);

    const float* x2 = xyz2 + (size_t)b * M_ * 3;
    for (int m = tid; m < M_; m += THREADS) {
        const float rr = rR[b * M_ + m];
        const float s  = ss[b * M_ + m];
        const float ratio = fminf(rr / (s + EPS), 1.f);
        sp[m] = make_float4(x2[3*m], x2[3*m+1], x2[3*m+2], rr * ratio);
        if (designated) {
            rR_next[b * M_ + m] = fmaxf(rr - s * ratio, 0.f);
            ss_next[b * M_ + m] = 0.f;
        }
    }
    __syncthreads();

    const int wave = tid >> 6, lane = tid & 63;
    const int nw = n0 + wave * ROWS_PER_WAVE;
    float cwave = 0.f;

    #pragma unroll 1
    for (int r = 0; r < ROWS_PER_WAVE; ++r) {
        const int idx = b * N_ + nw + r;
        const float* p1 = xyz1 + (size_t)idx * 3;
        const float x1 = p1[0], y1 = p1[1], z1 = p1[2];
        const float rl = rL[idx];
        const float rs = rowsum_g[idx];
        float accd = 0.f, accc = 0.f;
        #pragma unroll
        for (int k = 0; k < 32; ++k) {
            const float4 p = sp[lane + (k << 6)];
            const float dx = x1 - p.x, dy = y1 - p.y, dz = z1 - p.z;
            const float d2 = dx*dx + dy*dy + dz*dz;
            const float e = __expf(level * d2) * p.w;
            accd += e;
            accc += e * sqrtf(fmaxf(d2, 1e-20f));
        }
        #pragma unroll
        for (int off = 32; off >= 1; off >>= 1) {
            accd += __shfl_xor(accd, off, 64);
            accc += __shfl_xor(accc, off, 64);
        }
        if (lane == 0) {
            const float f = rl / (rs + EPS);
            rL[idx] = fmaxf(rl - f * accd, 0.f);
            cwave += f * accc;
        }
    }
    if (lane == 0) wcost[wave] = cwave;
    __syncthreads();
    if (tid == 0)
        atomicAdd(&out[b], wcost[0] + wcost[1] + wcost[2] + wcost[3]);
}

extern "C" void kernel_launch(void* const* d_in, const int* in_sizes, int n_in,
                              void* d_out, int out_size, void* d_ws, size_t ws_size,
                              hipStream_t stream) {
    const float* xyz1 = (const float*)d_in[0];
    const float* xyz2 = (const float*)d_in[1];
    float* out = (float*)d_out;
    float* ws = (float*)d_ws;
    const int SZ = B_ * N_;        // == B_*M_ == 16384
    float* rL     = ws;
    float* rowsum = ws + SZ;
    float* rRb[2] = { ws + 2 * SZ, ws + 3 * SZ };
    float* ssb[2] = { ws + 4 * SZ, ws + 5 * SZ };

    init_kernel<<<(SZ + THREADS - 1) / THREADS, THREADS, 0, stream>>>(
        rL, rRb[0], ssb[0], ssb[1], out);

    static const float levels[10] = {
        -16384.f, -4096.f, -1024.f, -256.f, -64.f,
        -16.f, -4.f, -1.f, -0.25f, 0.f
    };
    for (int s = 0; s < 10; ++s) {
        float* rR_cur  = rRb[s & 1];
        float* rR_next = rRb[(s + 1) & 1];
        float* ss_cur  = ssb[s & 1];
        float* ss_next = ssb[(s + 1) & 1];
        phase1<<<GRID, THREADS, 0, stream>>>(
            xyz1, xyz2, rL, rR_cur, ss_cur, rowsum, levels[s]);
        phase2<<<GRID, THREADS, 0, stream>>>(
            xyz1, xyz2, rL, rR_cur, rR_next, ss_cur, ss_next, rowsum, out, levels[s]);
    }
}